// Round 8
// baseline (106.228 us; speedup 1.0000x reference)
//
#include <hip/hip_runtime.h>

constexpr int B_   = 4;
constexpr int NL   = 8192;
constexpr int NH   = 2048;
constexpr int CH   = 256;
constexpr int CL   = 128;
constexpr int CIN  = 384;
constexpr int COUT = 256;

typedef _Float16 f16;
typedef _Float16 f16x8 __attribute__((ext_vector_type(8)));
typedef float    f32x4 __attribute__((ext_vector_type(4)));

// Branchless top-3 insert (strict < == earliest-index-wins on ties).
#define BINS(d, h, B0, B1, B2, I0, I1, I2) do {                              \
    bool m2_ = (d) < (B2); B2 = m2_ ? (d) : B2; I2 = m2_ ? (h) : I2;         \
    bool m1_ = (B2) < (B1);                                                  \
    { float t_ = B1; int ti_ = I1;                                           \
      B1 = m1_ ? B2 : B1; I1 = m1_ ? I2 : I1;                                \
      B2 = m1_ ? t_ : B2; I2 = m1_ ? ti_ : I2; }                             \
    bool m0_ = (B1) < (B0);                                                  \
    { float t_ = B0; int ti_ = I0;                                           \
      B0 = m0_ ? B1 : B0; I0 = m0_ ? I1 : I0;                                \
      B1 = m0_ ? t_ : B1; I1 = m0_ ? ti_ : I1; }                             \
} while (0)

// Exact top-3 VALUE update in 3 flat ops (depth-1): uses old b0/b1/b2.
#define VINS(d, B0, B1, B2) do {                                             \
    float nb2_ = __builtin_amdgcn_fmed3f(B1, B2, d);                         \
    float nb1_ = __builtin_amdgcn_fmed3f(B0, B1, d);                         \
    B0 = fminf(B0, d); B1 = nb1_; B2 = nb2_;                                 \
} while (0)

// ---------------------------------------------------------------------------
// K1: role-fused. blocks [0,512): two-pass 3-NN. [512,1024): fhT transpose.
// [1024,1408): W f32->f16.
// knn: wave w scans NH-slice [w*512,w*512+512) for the block's 64 low pts
// (lane = point); pts[h] is wave-uniform (LDS broadcast, conflict-free).
// Pass A: top-3 distances via min/med3 (3 ops). Merge -> global 3rd-smallest
// threshold. Pass B: bit-identical d2; full sequential insert only when
// d2 <= thr (~9% of iterations). Exact sequential tie semantics.
// ---------------------------------------------------------------------------
__global__ __launch_bounds__(256) void knn_prep_kernel(
    const float* __restrict__ xyz_low, const float* __restrict__ xyz_high,
    const float* __restrict__ feat_high, const float* __restrict__ Wm,
    f16* __restrict__ fhT, f16* __restrict__ Wh,
    int* __restrict__ idxG, float* __restrict__ wG)
{
    __shared__ __align__(16) char smraw[38016];
    const int bid = blockIdx.x, tid = threadIdx.x;

    if (bid < 512) {
        float4* pts = (float4*)smraw;                    // [0, 32768)
        float*  md  = (float*)(smraw + 32768);           // 64*13 f32
        float*  bc  = (float*)(smraw + 36096);           // 64 f32
        unsigned short* mi = (unsigned short*)(smraw + 36352); // 64*13 u16
        const int b = bid >> 7, l0 = (bid & 127) * 64;
        const int w = tid >> 6, p = tid & 63;

        const float* xh = xyz_high + (size_t)b * NH * 3;
        for (int h = tid; h < NH; h += 256) {
            float x = xh[h * 3], yy = xh[h * 3 + 1], z = xh[h * 3 + 2];
            pts[h] = make_float4(x, yy, z, x * x + yy * yy + z * z);
        }
        __syncthreads();

        const float* xl = xyz_low + ((size_t)b * NL + l0 + p) * 3;
        const float lx = xl[0], ly = xl[1], lz = xl[2];
        const float sl = lx * lx + ly * ly + lz * lz;
        const int h0 = w * 512;

        // ---- pass A: top-3 distance VALUES (3 flat ops/iter) ----
        float b0 = 1e30f, b1 = 1e30f, b2 = 1e30f;
        #pragma unroll 4
        for (int h = h0; h < h0 + 512; ++h) {
            float4 pt = pts[h];
            float d2 = fmaf(-2.0f, fmaf(lx, pt.x, fmaf(ly, pt.y, lz * pt.z)),
                            sl + pt.w);
            VINS(d2, b0, b1, b2);
        }
        const int cb = p * 13 + w * 3;
        md[cb] = b0; md[cb + 1] = b1; md[cb + 2] = b2;
        __syncthreads();

        if (tid < 64) {   // value-merge of 12 -> global 3rd-smallest
            float c0 = 1e30f, c1 = 1e30f, c2 = 1e30f;
            #pragma unroll
            for (int q = 0; q < 12; ++q) {
                float d = md[tid * 13 + q];
                VINS(d, c0, c1, c2);
            }
            bc[tid] = c2;
        }
        __syncthreads();

        // ---- pass B: index recovery, insert only when d2 <= thr ----
        const float thr = bc[p];
        float c0 = 1e30f, c1 = 1e30f, c2 = 1e30f;
        int j0 = 0, j1 = 0, j2 = 0;
        #pragma unroll 4
        for (int h = h0; h < h0 + 512; ++h) {
            float4 pt = pts[h];
            float d2 = fmaf(-2.0f, fmaf(lx, pt.x, fmaf(ly, pt.y, lz * pt.z)),
                            sl + pt.w);
            if (d2 <= thr) {
                BINS(d2, h, c0, c1, c2, j0, j1, j2);
            }
        }
        md[cb] = c0;     mi[cb] = (unsigned short)j0;
        md[cb + 1] = c1; mi[cb + 1] = (unsigned short)j1;
        md[cb + 2] = c2; mi[cb + 2] = (unsigned short)j2;
        __syncthreads();

        if (tid < 64) {   // final merge in slice order (exact tie semantics)
            float e0 = 1e30f, e1 = 1e30f, e2 = 1e30f;
            int j0f = 0, j1f = 0, j2f = 0;
            #pragma unroll
            for (int q = 0; q < 12; ++q) {
                float d = md[tid * 13 + q];
                int  ii = mi[tid * 13 + q];
                BINS(d, ii, e0, e1, e2, j0f, j1f, j2f);
            }
            float d0 = sqrtf(fmaxf(e0, 0.0f));
            float d1 = sqrtf(fmaxf(e1, 0.0f));
            float d2f = sqrtf(fmaxf(e2, 0.0f));
            float iw0 = 1.0f / fmaxf(d0, 1e-8f);
            float iw1 = 1.0f / fmaxf(d1, 1e-8f);
            float iw2 = 1.0f / fmaxf(d2f, 1e-8f);
            float sum = iw0 + iw1 + iw2;
            idxG[bid * 192 + tid]       = j0f;
            idxG[bid * 192 + 64 + tid]  = j1f;
            idxG[bid * 192 + 128 + tid] = j2f;
            wG[bid * 192 + tid]       = iw0 / sum;
            wG[bid * 192 + 64 + tid]  = iw1 / sum;
            wG[bid * 192 + 128 + tid] = iw2 / sum;
        }
    } else if (bid < 1024) {
        float (*tt)[33] = (float(*)[33])smraw;
        const int tx = tid & 31, ty = tid >> 5;
        #pragma unroll
        for (int k = 0; k < 4; ++k) {
            const int u  = (bid - 512) * 4 + k;        // 2048 tiles total
            const int ub = u >> 9, ut = u & 511;
            const int h0 = (ut & 63) * 32, c0 = (ut >> 6) * 32;
            #pragma unroll
            for (int pp = 0; pp < 4; ++pp)
                tt[ty + pp * 8][tx] =
                    feat_high[((size_t)ub * CH + c0 + ty + pp * 8) * NH + h0 + tx];
            __syncthreads();
            #pragma unroll
            for (int pp = 0; pp < 4; ++pp)
                fhT[((size_t)ub * NH + h0 + ty + pp * 8) * CH + c0 + tx] =
                    (f16)tt[tx][ty + pp * 8];
            __syncthreads();
        }
    } else {
        const int i = (bid - 1024) * 256 + tid;        // 384 blocks
        Wh[i] = (f16)Wm[i];
    }
}

// ---------------------------------------------------------------------------
// K2: interp gather -> As, barrier-free K-loop (W A-frags straight from
// global, L2-hot 192 KB; B-frags from LDS As), bias into acc, per-block BN
// partials, fp16 y staged through LDS for coalesced stores.
// ---------------------------------------------------------------------------
__global__ __launch_bounds__(256, 2) void gemm_kernel(
    const float* __restrict__ feat_low, const f16* __restrict__ fhT,
    const f16* __restrict__ Wh, const float* __restrict__ bias,
    const int* __restrict__ idxG, const float* __restrict__ wG,
    f16* __restrict__ yh, float* __restrict__ ps, float* __restrict__ psq)
{
    // As [0,50176) = [64][392] f16 ; idxL [50176,50944) ; wL [50944,51712)
    __shared__ __align__(16) char smraw[51712];
    f16*   As   = (f16*)smraw;
    int*   idxL = (int*)(smraw + 50176);
    float* wL   = (float*)(smraw + 50944);

    const int bid = blockIdx.x, tid = threadIdx.x;
    const int b = bid >> 7, l0 = (bid & 127) * 64;
    const int lane = tid & 63, w = tid >> 6;

    if (tid < 192) {
        idxL[tid] = idxG[bid * 192 + tid];
        wL[tid]   = wG [bid * 192 + tid];
    }
    __syncthreads();

    {   // prologue: interp gather (k<256) + feat_low direct staging (k>=256)
        const int p = tid >> 2, q = tid & 3;
        const int j0 = idxL[p], j1 = idxL[64 + p], j2 = idxL[128 + p];
        const float u0 = wL[p], u1 = wL[64 + p], u2 = wL[128 + p];
        const f16* r0 = fhT + ((size_t)b * NH + j0) * CH + q * 64;
        const f16* r1 = fhT + ((size_t)b * NH + j1) * CH + q * 64;
        const f16* r2 = fhT + ((size_t)b * NH + j2) * CH + q * 64;
        #pragma unroll
        for (int j = 0; j < 8; ++j) {
            f16x8 v0 = *(const f16x8*)(r0 + j * 8);
            f16x8 v1 = *(const f16x8*)(r1 + j * 8);
            f16x8 v2 = *(const f16x8*)(r2 + j * 8);
            f16x8 o;
            #pragma unroll
            for (int e = 0; e < 8; ++e)
                o[e] = (f16)(u0 * (float)v0[e] + u1 * (float)v1[e]
                             + u2 * (float)v2[e]);
            *(f16x8*)&As[p * 392 + q * 64 + j * 8] = o;
        }
        const float* flb = feat_low + ((size_t)b * CL + q * 32) * NL + l0 + p;
        f16 tmp[32];
        #pragma unroll
        for (int i = 0; i < 32; ++i)
            tmp[i] = (f16)flb[(size_t)i * NL];
        #pragma unroll
        for (int j = 0; j < 4; ++j)
            *(f16x8*)&As[p * 392 + 256 + q * 32 + j * 8] =
                *(const f16x8*)&tmp[j * 8];
    }
    __syncthreads();

    f32x4 acc[4][4] = {};
    const int kb = (lane >> 4) * 8;
    const int r  = lane & 15;
    #pragma unroll
    for (int kt = 0; kt < 12; ++kt) {
        const int k0 = kt * 32;
        f16x8 a[4], bb[4];
        #pragma unroll
        for (int mi = 0; mi < 4; ++mi)
            a[mi] = *(const f16x8*)&Wh[(size_t)(w * 64 + mi * 16 + r) * CIN
                                       + k0 + kb];
        #pragma unroll
        for (int ni = 0; ni < 4; ++ni)
            bb[ni] = *(const f16x8*)&As[(ni * 16 + r) * 392 + k0 + kb];
        #pragma unroll
        for (int mi = 0; mi < 4; ++mi)
            #pragma unroll
            for (int ni = 0; ni < 4; ++ni)
                acc[mi][ni] = __builtin_amdgcn_mfma_f32_16x16x32_f16(
                    a[mi], bb[ni], acc[mi][ni], 0, 0, 0);
    }

    // bias into acc + per-block BN partials (no LDS touched)
    const int r4 = (lane >> 4) * 4, cl = lane & 15;
    #pragma unroll
    for (int mi = 0; mi < 4; ++mi) {
        #pragma unroll
        for (int j = 0; j < 4; ++j) {
            const int o = w * 64 + mi * 16 + r4 + j;
            const float bi = bias[o];
            float s = 0.0f, sq = 0.0f;
            #pragma unroll
            for (int ni = 0; ni < 4; ++ni) {
                acc[mi][ni][j] += bi;
                float v = acc[mi][ni][j];
                s += v; sq += v * v;
            }
            #pragma unroll
            for (int m = 1; m < 16; m <<= 1) {
                s  += __shfl_xor(s, m);
                sq += __shfl_xor(sq, m);
            }
            if (cl == 0) {
                ps [o * 512 + bid] = s;
                psq[o * 512 + bid] = sq;
            }
        }
    }
    __syncthreads();   // all As reads done -> safe to alias with Ys

    f16* Ys = (f16*)smraw;             // [256][72] f16 = 36864 B
    #pragma unroll
    for (int mi = 0; mi < 4; ++mi)
        #pragma unroll
        for (int j = 0; j < 4; ++j) {
            const int o = w * 64 + mi * 16 + r4 + j;
            #pragma unroll
            for (int ni = 0; ni < 4; ++ni)
                Ys[o * 72 + cl + ni * 16] = (f16)acc[mi][ni][j];
        }
    __syncthreads();
    const int q = tid & 3;
    #pragma unroll
    for (int rep = 0; rep < 4; ++rep) {
        const int o = rep * 64 + (tid >> 2);
        f16* dst = yh + ((size_t)b * COUT + o) * NL + l0 + q * 16;
        *(f16x8*)(dst)     = *(const f16x8*)&Ys[o * 72 + q * 16];
        *(f16x8*)(dst + 8) = *(const f16x8*)&Ys[o * 72 + q * 16 + 8];
    }
}

// ---------------------------------------------------------------------------
// K3: fused BN stats + apply + ReLU. Grid (COUT, B_): each block reduces its
// channel's 512 partials (deterministic, redundant across the 4 b-blocks of
// a channel -> identical results) then applies to its (b,o) row of 8192.
// ---------------------------------------------------------------------------
__global__ __launch_bounds__(256) void stats_apply_kernel(
    const float* __restrict__ ps, const float* __restrict__ psq,
    const f16* __restrict__ yh,
    const float* __restrict__ gamma, const float* __restrict__ beta,
    float* __restrict__ y)
{
    const int o = blockIdx.x, b = blockIdx.y, tid = threadIdx.x;
    const int w = tid >> 6, lane = tid & 63;

    float s = ps[o * 512 + tid] + ps[o * 512 + 256 + tid];
    float q = psq[o * 512 + tid] + psq[o * 512 + 256 + tid];
    #pragma unroll
    for (int m = 32; m > 0; m >>= 1) {
        s += __shfl_down(s, m);
        q += __shfl_down(q, m);
    }
    __shared__ float red[8];
    if (lane == 0) { red[w] = s; red[4 + w] = q; }
    __syncthreads();
    s = red[0] + red[1] + red[2] + red[3];
    q = red[4] + red[5] + red[6] + red[7];
    const float n  = (float)(B_ * NL);
    const float mu = s / n;
    const float rs = rsqrtf(q / n - mu * mu + 1e-5f);
    const float g  = gamma[o], be = beta[o];

    const f16* src = yh + ((size_t)b * COUT + o) * NL;
    float*     dst = y  + ((size_t)b * COUT + o) * NL;
    #pragma unroll
    for (int it = 0; it < 4; ++it) {
        const int base = it * 2048 + tid * 8;
        f16x8 v = *(const f16x8*)(src + base);
        float4 o1, o2;
        o1.x = fmaxf(fmaf(g, ((float)v[0] - mu) * rs, be), 0.0f);
        o1.y = fmaxf(fmaf(g, ((float)v[1] - mu) * rs, be), 0.0f);
        o1.z = fmaxf(fmaf(g, ((float)v[2] - mu) * rs, be), 0.0f);
        o1.w = fmaxf(fmaf(g, ((float)v[3] - mu) * rs, be), 0.0f);
        o2.x = fmaxf(fmaf(g, ((float)v[4] - mu) * rs, be), 0.0f);
        o2.y = fmaxf(fmaf(g, ((float)v[5] - mu) * rs, be), 0.0f);
        o2.z = fmaxf(fmaf(g, ((float)v[6] - mu) * rs, be), 0.0f);
        o2.w = fmaxf(fmaf(g, ((float)v[7] - mu) * rs, be), 0.0f);
        *(float4*)(dst + base)     = o1;
        *(float4*)(dst + base + 4) = o2;
    }
}

// ---------------------------------------------------------------------------
extern "C" void kernel_launch(void* const* d_in, const int* in_sizes, int n_in,
                              void* d_out, int out_size, void* d_ws, size_t ws_size,
                              hipStream_t stream)
{
    const float* xyz_low   = (const float*)d_in[0];
    const float* xyz_high  = (const float*)d_in[1];
    const float* feat_low  = (const float*)d_in[2];
    const float* feat_high = (const float*)d_in[3];
    const float* Wm        = (const float*)d_in[4];
    const float* bias      = (const float*)d_in[5];
    const float* gamma     = (const float*)d_in[6];
    const float* beta      = (const float*)d_in[7];
    float* y = (float*)d_out;

    float* ps   = (float*)d_ws;                        // 256*512 f32
    float* psq  = ps + (size_t)COUT * 512;             // 256*512 f32
    int*   idxG = (int*)(psq + (size_t)COUT * 512);    // 512*192 int
    float* wG   = (float*)(idxG + 512 * 192);          // 512*192 f32
    f16*   Wh   = (f16*)(wG + 512 * 192);              // 256*384 f16
    f16*   fhT  = Wh + (size_t)COUT * CIN;             // 4*2048*256 f16 (4.2MB)
    f16*   yh   = fhT + (size_t)B_ * NH * CH;          // 4*256*8192 f16 (16.8MB)

    knn_prep_kernel<<<1408, 256, 0, stream>>>(
        xyz_low, xyz_high, feat_high, Wm, fhT, Wh, idxG, wG);
    gemm_kernel<<<512, 256, 0, stream>>>(
        feat_low, fhT, Wh, bias, idxG, wG, yh, ps, psq);
    stats_apply_kernel<<<dim3(COUT, B_), 256, 0, stream>>>(
        ps, psq, yh, gamma, beta, y);
}

// Round 9
// 84.061 us; speedup vs baseline: 1.2637x; 1.2637x over previous
//
#include <hip/hip_runtime.h>

constexpr int B_   = 4;
constexpr int NL   = 8192;
constexpr int NH   = 2048;
constexpr int CH   = 256;
constexpr int CL   = 128;
constexpr int CIN  = 384;
constexpr int COUT = 256;

typedef _Float16 f16;
typedef _Float16 f16x8 __attribute__((ext_vector_type(8)));
typedef float    f32x4 __attribute__((ext_vector_type(4)));

// Branchless top-3 insert (strict < == earliest-index-wins on ties).
#define BINS(d, h, B0, B1, B2, I0, I1, I2) do {                              \
    bool m2_ = (d) < (B2); B2 = m2_ ? (d) : B2; I2 = m2_ ? (h) : I2;         \
    bool m1_ = (B2) < (B1);                                                  \
    { float t_ = B1; int ti_ = I1;                                           \
      B1 = m1_ ? B2 : B1; I1 = m1_ ? I2 : I1;                                \
      B2 = m1_ ? t_ : B2; I2 = m1_ ? ti_ : I2; }                             \
    bool m0_ = (B1) < (B0);                                                  \
    { float t_ = B0; int ti_ = I0;                                           \
      B0 = m0_ ? B1 : B0; I0 = m0_ ? I1 : I0;                                \
      B1 = m0_ ? t_ : B1; I1 = m0_ ? ti_ : I1; }                             \
} while (0)

// ---------------------------------------------------------------------------
// K1: role-fused.
//   [0,1024):    3-NN half-range blocks. Block = (tile<<1)|half; covers the
//                tile's 64 low points against h in [half*1024, half*1024+1024).
//                Wave w scans 256-h slice (pts[h] wave-uniform -> broadcast).
//                12-way slice-order merge -> top-3 (d2, idx) per point per
//                half, written RAW to cdG/ciG (weights computed in K2).
//   [1024,1536): fhT transpose (B,CH,NH) f32 -> (B,NH,CH) f16.
//   [1536,1920): W f32 -> f16.
// 21.4 KB LDS -> 7 blocks/CU; knn-only occupancy 4 blocks/CU = 16 waves/CU.
// ---------------------------------------------------------------------------
__global__ __launch_bounds__(256) void knn_prep_kernel(
    const float* __restrict__ xyz_low, const float* __restrict__ xyz_high,
    const float* __restrict__ feat_high, const float* __restrict__ Wm,
    f16* __restrict__ fhT, f16* __restrict__ Wh,
    float* __restrict__ cdG, int* __restrict__ ciG)
{
    __shared__ __align__(16) char smraw[21376];
    const int bid = blockIdx.x, tid = threadIdx.x;

    if (bid < 1024) {
        float4*         pts = (float4*)smraw;                   // [0,16384)
        float*          md  = (float*)(smraw + 16384);          // 64*13 f32
        unsigned short* mi  = (unsigned short*)(smraw + 19712); // 64*13 u16
        const int tile = bid >> 1, half = bid & 1;
        const int b = tile >> 7, l0 = (tile & 127) * 64;
        const int w = tid >> 6, p = tid & 63;
        const int hbase = half * 1024;

        const float* xh = xyz_high + ((size_t)b * NH + hbase) * 3;
        for (int h = tid; h < 1024; h += 256) {
            float x = xh[h * 3], yy = xh[h * 3 + 1], z = xh[h * 3 + 2];
            pts[h] = make_float4(x, yy, z, x * x + yy * yy + z * z);
        }
        __syncthreads();

        const float* xl = xyz_low + ((size_t)b * NL + l0 + p) * 3;
        const float lx = xl[0], ly = xl[1], lz = xl[2];
        const float sl = lx * lx + ly * ly + lz * lz;

        float b0 = 1e30f, b1 = 1e30f, b2 = 1e30f;
        int i0 = 0, i1 = 0, i2 = 0;
        const int h0 = w * 256;
        #pragma unroll 8
        for (int h = h0; h < h0 + 256; ++h) {
            float4 pt = pts[h];
            float d2 = fmaf(-2.0f, fmaf(lx, pt.x, fmaf(ly, pt.y, lz * pt.z)),
                            sl + pt.w);
            BINS(d2, h, b0, b1, b2, i0, i1, i2);
        }
        const int cb = p * 13 + w * 3;
        md[cb] = b0;     mi[cb] = (unsigned short)(hbase + i0);
        md[cb + 1] = b1; mi[cb + 1] = (unsigned short)(hbase + i1);
        md[cb + 2] = b2; mi[cb + 2] = (unsigned short)(hbase + i2);
        __syncthreads();

        if (tid < 64) {   // merge 12 in slice order (h ascending, tie-stable)
            float e0 = 1e30f, e1 = 1e30f, e2 = 1e30f;
            int j0 = 0, j1 = 0, j2 = 0;
            #pragma unroll
            for (int q = 0; q < 12; ++q) {
                float d = md[tid * 13 + q];
                int  ii = mi[tid * 13 + q];
                BINS(d, ii, e0, e1, e2, j0, j1, j2);
            }
            const size_t dst = (size_t)bid * 192 + tid;
            cdG[dst]       = e0; ciG[dst]       = j0;
            cdG[dst + 64]  = e1; ciG[dst + 64]  = j1;
            cdG[dst + 128] = e2; ciG[dst + 128] = j2;
        }
    } else if (bid < 1536) {
        float (*tt)[33] = (float(*)[33])smraw;
        const int tx = tid & 31, ty = tid >> 5;
        #pragma unroll
        for (int k = 0; k < 4; ++k) {
            const int u  = (bid - 1024) * 4 + k;       // 2048 tiles total
            const int ub = u >> 9, ut = u & 511;
            const int h0 = (ut & 63) * 32, c0 = (ut >> 6) * 32;
            #pragma unroll
            for (int pp = 0; pp < 4; ++pp)
                tt[ty + pp * 8][tx] =
                    feat_high[((size_t)ub * CH + c0 + ty + pp * 8) * NH + h0 + tx];
            __syncthreads();
            #pragma unroll
            for (int pp = 0; pp < 4; ++pp)
                fhT[((size_t)ub * NH + h0 + ty + pp * 8) * CH + c0 + tx] =
                    (f16)tt[tx][ty + pp * 8];
            __syncthreads();
        }
    } else {
        const int i = (bid - 1536) * 256 + tid;        // 384 blocks
        Wh[i] = (f16)Wm[i];
    }
}

// ---------------------------------------------------------------------------
// K2: merge the 2 half-range candidate triples (half0 first, strict < ->
// exact sequential tie semantics) -> weights; interp gather -> As;
// barrier-free K-loop (W A-frags from L2-hot global; B-frags from LDS As);
// bias into acc; per-block BN partials; fp16 y via LDS-coalesced stores.
// ---------------------------------------------------------------------------
__global__ __launch_bounds__(256, 2) void gemm_kernel(
    const float* __restrict__ feat_low, const f16* __restrict__ fhT,
    const f16* __restrict__ Wh, const float* __restrict__ bias,
    const float* __restrict__ cdG, const int* __restrict__ ciG,
    f16* __restrict__ yh, float* __restrict__ ps, float* __restrict__ psq)
{
    // As [0,50176) = [64][392] f16 ; idxL [50176,50944) ; wL [50944,51712)
    __shared__ __align__(16) char smraw[51712];
    f16*   As   = (f16*)smraw;
    int*   idxL = (int*)(smraw + 50176);
    float* wL   = (float*)(smraw + 50944);

    const int bid = blockIdx.x, tid = threadIdx.x;
    const int b = bid >> 7, l0 = (bid & 127) * 64;
    const int lane = tid & 63, w = tid >> 6;

    if (tid < 64) {   // final cross-half merge + weights
        float e0 = 1e30f, e1 = 1e30f, e2 = 1e30f;
        int j0 = 0, j1 = 0, j2 = 0;
        #pragma unroll
        for (int hb = 0; hb < 2; ++hb) {
            const size_t src = (size_t)(bid * 2 + hb) * 192 + tid;
            #pragma unroll
            for (int q = 0; q < 3; ++q) {
                float d = cdG[src + q * 64];
                int  ii = ciG[src + q * 64];
                BINS(d, ii, e0, e1, e2, j0, j1, j2);
            }
        }
        float d0 = sqrtf(fmaxf(e0, 0.0f));
        float d1 = sqrtf(fmaxf(e1, 0.0f));
        float d2f = sqrtf(fmaxf(e2, 0.0f));
        float iw0 = 1.0f / fmaxf(d0, 1e-8f);
        float iw1 = 1.0f / fmaxf(d1, 1e-8f);
        float iw2 = 1.0f / fmaxf(d2f, 1e-8f);
        float sum = iw0 + iw1 + iw2;
        idxL[tid] = j0; idxL[64 + tid] = j1; idxL[128 + tid] = j2;
        wL[tid] = iw0 / sum; wL[64 + tid] = iw1 / sum; wL[128 + tid] = iw2 / sum;
    }
    __syncthreads();

    {   // prologue: interp gather (k<256) + feat_low direct staging (k>=256)
        const int p = tid >> 2, q = tid & 3;
        const int j0 = idxL[p], j1 = idxL[64 + p], j2 = idxL[128 + p];
        const float u0 = wL[p], u1 = wL[64 + p], u2 = wL[128 + p];
        const f16* r0 = fhT + ((size_t)b * NH + j0) * CH + q * 64;
        const f16* r1 = fhT + ((size_t)b * NH + j1) * CH + q * 64;
        const f16* r2 = fhT + ((size_t)b * NH + j2) * CH + q * 64;
        #pragma unroll
        for (int j = 0; j < 8; ++j) {
            f16x8 v0 = *(const f16x8*)(r0 + j * 8);
            f16x8 v1 = *(const f16x8*)(r1 + j * 8);
            f16x8 v2 = *(const f16x8*)(r2 + j * 8);
            f16x8 o;
            #pragma unroll
            for (int e = 0; e < 8; ++e)
                o[e] = (f16)(u0 * (float)v0[e] + u1 * (float)v1[e]
                             + u2 * (float)v2[e]);
            *(f16x8*)&As[p * 392 + q * 64 + j * 8] = o;
        }
        const float* flb = feat_low + ((size_t)b * CL + q * 32) * NL + l0 + p;
        f16 tmp[32];
        #pragma unroll
        for (int i = 0; i < 32; ++i)
            tmp[i] = (f16)flb[(size_t)i * NL];
        #pragma unroll
        for (int j = 0; j < 4; ++j)
            *(f16x8*)&As[p * 392 + 256 + q * 32 + j * 8] =
                *(const f16x8*)&tmp[j * 8];
    }
    __syncthreads();

    f32x4 acc[4][4] = {};
    const int kb = (lane >> 4) * 8;
    const int r  = lane & 15;
    #pragma unroll
    for (int kt = 0; kt < 12; ++kt) {
        const int k0 = kt * 32;
        f16x8 a[4], bb[4];
        #pragma unroll
        for (int mi = 0; mi < 4; ++mi)
            a[mi] = *(const f16x8*)&Wh[(size_t)(w * 64 + mi * 16 + r) * CIN
                                       + k0 + kb];
        #pragma unroll
        for (int ni = 0; ni < 4; ++ni)
            bb[ni] = *(const f16x8*)&As[(ni * 16 + r) * 392 + k0 + kb];
        #pragma unroll
        for (int mi = 0; mi < 4; ++mi)
            #pragma unroll
            for (int ni = 0; ni < 4; ++ni)
                acc[mi][ni] = __builtin_amdgcn_mfma_f32_16x16x32_f16(
                    a[mi], bb[ni], acc[mi][ni], 0, 0, 0);
    }

    // bias into acc + per-block BN partials (no LDS touched)
    const int r4 = (lane >> 4) * 4, cl = lane & 15;
    #pragma unroll
    for (int mi = 0; mi < 4; ++mi) {
        #pragma unroll
        for (int j = 0; j < 4; ++j) {
            const int o = w * 64 + mi * 16 + r4 + j;
            const float bi = bias[o];
            float s = 0.0f, sq = 0.0f;
            #pragma unroll
            for (int ni = 0; ni < 4; ++ni) {
                acc[mi][ni][j] += bi;
                float v = acc[mi][ni][j];
                s += v; sq += v * v;
            }
            #pragma unroll
            for (int m = 1; m < 16; m <<= 1) {
                s  += __shfl_xor(s, m);
                sq += __shfl_xor(sq, m);
            }
            if (cl == 0) {
                ps [o * 512 + bid] = s;
                psq[o * 512 + bid] = sq;
            }
        }
    }
    __syncthreads();   // all As reads done -> safe to alias with Ys

    f16* Ys = (f16*)smraw;             // [256][72] f16 = 36864 B
    #pragma unroll
    for (int mi = 0; mi < 4; ++mi)
        #pragma unroll
        for (int j = 0; j < 4; ++j) {
            const int o = w * 64 + mi * 16 + r4 + j;
            #pragma unroll
            for (int ni = 0; ni < 4; ++ni)
                Ys[o * 72 + cl + ni * 16] = (f16)acc[mi][ni][j];
        }
    __syncthreads();
    const int q = tid & 3;
    #pragma unroll
    for (int rep = 0; rep < 4; ++rep) {
        const int o = rep * 64 + (tid >> 2);
        f16* dst = yh + ((size_t)b * COUT + o) * NL + l0 + q * 16;
        *(f16x8*)(dst)     = *(const f16x8*)&Ys[o * 72 + q * 16];
        *(f16x8*)(dst + 8) = *(const f16x8*)&Ys[o * 72 + q * 16 + 8];
    }
}

// ---------------------------------------------------------------------------
// K3: fused BN stats + apply + ReLU. Grid (COUT, B_): each block reduces its
// channel's 512 partials (deterministic, redundant across the 4 b-blocks of
// a channel -> identical results) then applies to its (b,o) row of 8192.
// ---------------------------------------------------------------------------
__global__ __launch_bounds__(256) void stats_apply_kernel(
    const float* __restrict__ ps, const float* __restrict__ psq,
    const f16* __restrict__ yh,
    const float* __restrict__ gamma, const float* __restrict__ beta,
    float* __restrict__ y)
{
    const int o = blockIdx.x, b = blockIdx.y, tid = threadIdx.x;
    const int w = tid >> 6, lane = tid & 63;

    float s = ps[o * 512 + tid] + ps[o * 512 + 256 + tid];
    float q = psq[o * 512 + tid] + psq[o * 512 + 256 + tid];
    #pragma unroll
    for (int m = 32; m > 0; m >>= 1) {
        s += __shfl_down(s, m);
        q += __shfl_down(q, m);
    }
    __shared__ float red[8];
    if (lane == 0) { red[w] = s; red[4 + w] = q; }
    __syncthreads();
    s = red[0] + red[1] + red[2] + red[3];
    q = red[4] + red[5] + red[6] + red[7];
    const float n  = (float)(B_ * NL);
    const float mu = s / n;
    const float rs = rsqrtf(q / n - mu * mu + 1e-5f);
    const float g  = gamma[o], be = beta[o];

    const f16* src = yh + ((size_t)b * COUT + o) * NL;
    float*     dst = y  + ((size_t)b * COUT + o) * NL;
    #pragma unroll
    for (int it = 0; it < 4; ++it) {
        const int base = it * 2048 + tid * 8;
        f16x8 v = *(const f16x8*)(src + base);
        float4 o1, o2;
        o1.x = fmaxf(fmaf(g, ((float)v[0] - mu) * rs, be), 0.0f);
        o1.y = fmaxf(fmaf(g, ((float)v[1] - mu) * rs, be), 0.0f);
        o1.z = fmaxf(fmaf(g, ((float)v[2] - mu) * rs, be), 0.0f);
        o1.w = fmaxf(fmaf(g, ((float)v[3] - mu) * rs, be), 0.0f);
        o2.x = fmaxf(fmaf(g, ((float)v[4] - mu) * rs, be), 0.0f);
        o2.y = fmaxf(fmaf(g, ((float)v[5] - mu) * rs, be), 0.0f);
        o2.z = fmaxf(fmaf(g, ((float)v[6] - mu) * rs, be), 0.0f);
        o2.w = fmaxf(fmaf(g, ((float)v[7] - mu) * rs, be), 0.0f);
        *(float4*)(dst + base)     = o1;
        *(float4*)(dst + base + 4) = o2;
    }
}

// ---------------------------------------------------------------------------
extern "C" void kernel_launch(void* const* d_in, const int* in_sizes, int n_in,
                              void* d_out, int out_size, void* d_ws, size_t ws_size,
                              hipStream_t stream)
{
    const float* xyz_low   = (const float*)d_in[0];
    const float* xyz_high  = (const float*)d_in[1];
    const float* feat_low  = (const float*)d_in[2];
    const float* feat_high = (const float*)d_in[3];
    const float* Wm        = (const float*)d_in[4];
    const float* bias      = (const float*)d_in[5];
    const float* gamma     = (const float*)d_in[6];
    const float* beta      = (const float*)d_in[7];
    float* y = (float*)d_out;

    float* ps   = (float*)d_ws;                        // 256*512 f32
    float* psq  = ps + (size_t)COUT * 512;             // 256*512 f32
    float* cdG  = psq + (size_t)COUT * 512;            // 1024*192 f32
    int*   ciG  = (int*)(cdG + (size_t)1024 * 192);    // 1024*192 i32
    f16*   Wh   = (f16*)(ciG + (size_t)1024 * 192);    // 256*384 f16
    f16*   fhT  = Wh + (size_t)COUT * CIN;             // 4*2048*256 f16 (4.2MB)
    f16*   yh   = fhT + (size_t)B_ * NH * CH;          // 4*256*8192 f16 (16.8MB)

    knn_prep_kernel<<<1920, 256, 0, stream>>>(
        xyz_low, xyz_high, feat_high, Wm, fhT, Wh, cdG, ciG);
    gemm_kernel<<<512, 256, 0, stream>>>(
        feat_low, fhT, Wh, bias, cdG, ciG, yh, ps, psq);
    stats_apply_kernel<<<dim3(COUT, B_), 256, 0, stream>>>(
        ps, psq, yh, gamma, beta, y);
}